// Round 7
// baseline (225.786 us; speedup 1.0000x reference)
//
#include <hip/hip_runtime.h>

typedef _Float16 f16x8 __attribute__((ext_vector_type(8)));
typedef _Float16 f16x4 __attribute__((ext_vector_type(4)));
typedef _Float16 h2   __attribute__((ext_vector_type(2)));
typedef float f32x4 __attribute__((ext_vector_type(4)));

__device__ __forceinline__ void gload16(const void* g, void* l) {
  __builtin_amdgcn_global_load_lds(
      (__attribute__((address_space(1))) void*)g,
      (__attribute__((address_space(3))) void*)l, 16, 0, 0);
}

// W is scaled by 2^12 when cast to f16 (raw ~1e-5 values are f16-subnormal;
// denormal flush would delete the r@W term). Epilogue multiplies by 2^-12.
#define W_SCALE 4096.0f
#define W_UNSCALE (1.0f / 4096.0f)

// "Island" operand layout for MFMA staging (conflict-free LDS by construction):
// element (row,k) of a [*][3136] f16 matrix lives at
//   (row>>4)*50176 + (k>>5)*512 + ((k>>3)&3)*128 + (row&15)*8 + (k&7)
// i.e. each 16-row x 32-k chunk is stored [kgroup 0..3][row 0..15][elem 0..7].
// A wave's global_load_lds (lane i reads 16B at base+i*16B) then lands LDS
// linearly with lane i = (kgroup=i>>4, row=i&15) -- exactly the 16x16x32 MFMA
// fragment feed, and frag ds_read_b128 banks = (lane&15)*4 -> 2-way (free).
#define ISL(row, k) (((row) >> 4) * 50176 + ((k) >> 5) * 512 + \
                     ((((k) >> 3) & 3) << 7) + (((row) & 15) << 3) + ((k) & 7))

// ---------------- conv 3x3 (1->16) + bias + relu + maxpool2 -> A' (island f16) ----------------
// one thread per (b, pooled pixel); 16 channels; packed-f16 pool-pair math.
__global__ __launch_bounds__(256) void conv_pool_kernel(
    const float* __restrict__ x,      // [8192][28][28]
    const float* __restrict__ cw,     // [16][9]
    const float* __restrict__ cb,     // [16]
    _Float16* __restrict__ out) {     // A' island layout, logical [8192][3136]
  __shared__ h2 wsm[144];
  __shared__ h2 bsm[16];
  int tid = threadIdx.x;
  if (tid < 144) { float w = cw[tid]; wsm[tid] = h2{(_Float16)w, (_Float16)w}; }
  if (tid < 16)  { float b = cb[tid]; bsm[tid] = h2{(_Float16)b, (_Float16)b}; }
  __syncthreads();
  if (tid >= 196) return;
  int b = blockIdx.x;
  int ph = tid / 14, pw = tid - ph * 14;
  const float* xb = x + b * 784;
  float xv[4][4];
  int r0 = 2 * ph - 1, c0 = 2 * pw - 1;
#pragma unroll
  for (int i = 0; i < 4; ++i) {
    int r = r0 + i;
#pragma unroll
    for (int j = 0; j < 4; ++j) {
      int c = c0 + j;
      xv[i][j] = (r >= 0 && r < 28 && c >= 0 && c < 28) ? xb[r * 28 + c] : 0.f;
    }
  }
  // packed taps: xp[i][j] = (xv[i][j], xv[i][j+1]) feeds conv px pair (c, c+1)
  h2 xp[4][3];
#pragma unroll
  for (int i = 0; i < 4; ++i)
#pragma unroll
    for (int j = 0; j < 3; ++j)
      xp[i][j] = h2{(_Float16)xv[i][j], (_Float16)xv[i][j + 1]};

  int outbase = (b >> 4) * 50176 + ((b & 15) << 3);
#pragma unroll
  for (int ch = 0; ch < 16; ++ch) {
    h2 a01 = bsm[ch], a23 = bsm[ch];
#pragma unroll
    for (int i = 0; i < 3; ++i)
#pragma unroll
      for (int j = 0; j < 3; ++j) {
        h2 wv = wsm[ch * 9 + i * 3 + j];
        a01 = __builtin_elementwise_fma(wv, xp[i][j], a01);
        a23 = __builtin_elementwise_fma(wv, xp[i + 1][j], a23);
      }
    h2 m2 = __builtin_elementwise_max(a01, a23);
    _Float16 m = m2[0] > m2[1] ? m2[0] : m2[1];
    m = m > (_Float16)0.f ? m : (_Float16)0.f;  // relu(max) == max(relu)
    int k = ch * 196 + tid;
    out[outbase + ((k >> 5) << 9) + ((((k) >> 3) & 3) << 7) + (k & 7)] = m;
  }
}

// ---------------- W_in fp32 -> f16 island layout ----------------
// one block per n-row (256 blocks)
__global__ __launch_bounds__(256) void win_cvt_kernel(
    const float* __restrict__ in,     // [256][3136]
    _Float16* __restrict__ out) {     // B' island layout, logical [256][3136]
  int n = blockIdx.x, tid = threadIdx.x;
  const float* src = in + (size_t)n * 3136;
#pragma unroll
  for (int it = 0; it < 4; ++it) {
    int idx = it * 256 + tid;          // float4 index, 784 per row
    if (idx < 784) {
      int k0 = idx * 4;                // k0&7 in {0,4}: stays inside one 8-island
      float4 v = *(const float4*)(src + k0);
      f16x4 h = {(_Float16)v.x, (_Float16)v.y, (_Float16)v.z, (_Float16)v.w};
      *(f16x4*)(out + ISL(n, k0)) = h;
    }
  }
}

// W [256][256] (k-major) -> Wt f16 [n][k] (n-major, plain), scaled by 2^12
__global__ void wt_cvt_kernel(const float* __restrict__ W,
                              _Float16* __restrict__ Wt) {
  int i = blockIdx.x * 256 + threadIdx.x;  // 65536
  int k = i >> 8, n = i & 255;             // coalesced read of W row k
  Wt[n * 256 + k] = (_Float16)(W[k * 256 + n] * W_SCALE);
}

// ---------------- Rf init: Z[m][n] = b_in[n] (atomic accumulation target) ----------------
__global__ void init_rf_kernel(const float* __restrict__ b_in,
                               float* __restrict__ Rf) {
  int idx = blockIdx.x * 256 + threadIdx.x;      // 524288 float4
  float4 b4 = ((const float4*)b_in)[idx & 63];
  ((float4*)Rf)[idx] = b4;
}

// ---------------- GEMM1 split-K: Z += A[64 rows] @ W_in^T[128 cols], k-chunk of 448 ----------------
// grid (128, 2, 7); tile 64x128, BK=32, 14 steps; 4 waves, each 32x64 (2x4 frags).
// Epilogue: device-scope f32 atomic add into Z (bias pre-initialized).
__global__ __launch_bounds__(256) void gemm1_kernel(
    const _Float16* __restrict__ A,   // A' island, logical [8192][3136]
    const _Float16* __restrict__ Bw,  // B' island, logical [256][3136]
    float* __restrict__ Rf) {         // Z [8192][256]
  __shared__ __align__(16) _Float16 As[2048];   // 4 chunks [kg][rr][8]
  __shared__ __align__(16) _Float16 Bs[4096];   // 8 chunks
  int tid = threadIdx.x, lane = tid & 63, wid = tid >> 6;
  int bm = blockIdx.x * 64, bn = blockIdx.y * 128;
  f32x4 acc[2][4];
#pragma unroll
  for (int i = 0; i < 2; ++i)
#pragma unroll
    for (int j = 0; j < 4; ++j) acc[i][j] = (f32x4){0.f, 0.f, 0.f, 0.f};

  const _Float16* Ag  = A  + ((bm >> 4) + wid) * 50176 + lane * 8;
  const _Float16* Bg0 = Bw + ((bn >> 4) + 2 * wid) * 50176 + lane * 8;
  const _Float16* Bg1 = Bg0 + 50176;
  _Float16* Asw  = As + wid * 512;
  _Float16* Bsw0 = Bs + 2 * wid * 512;
  _Float16* Bsw1 = Bsw0 + 512;

  int c0 = blockIdx.z * 14;                    // k-chunk range [c0, c0+14)
  int rko = ((lane >> 4) << 7) + ((lane & 15) << 3);
  int ga = (wid & 1) * 2, gb = (wid >> 1) * 4;
  for (int t = 0; t < 14; ++t) {
    int coff = (c0 + t) * 512;
    __syncthreads();                           // prev readers done
    gload16(Ag + coff, Asw);
    gload16(Bg0 + coff, Bsw0);
    gload16(Bg1 + coff, Bsw1);
    __syncthreads();                           // vmcnt(0) drain (hidden by ~7 blocks/CU TLP)
    f16x8 af[2];
#pragma unroll
    for (int mi = 0; mi < 2; ++mi)
      af[mi] = *(const f16x8*)(As + (ga + mi) * 512 + rko);
#pragma unroll
    for (int ni = 0; ni < 4; ++ni) {
      f16x8 bf = *(const f16x8*)(Bs + (gb + ni) * 512 + rko);
      acc[0][ni] = __builtin_amdgcn_mfma_f32_16x16x32_f16(af[0], bf, acc[0][ni], 0, 0, 0);
      acc[1][ni] = __builtin_amdgcn_mfma_f32_16x16x32_f16(af[1], bf, acc[1][ni], 0, 0, 0);
    }
  }
  int wm = (wid & 1) * 32, wn = (wid >> 1) * 64;
  int rg = (lane >> 4) * 4, cl = lane & 15;
#pragma unroll
  for (int mi = 0; mi < 2; ++mi)
#pragma unroll
    for (int ni = 0; ni < 4; ++ni)
#pragma unroll
      for (int j = 0; j < 4; ++j) {
        int m = bm + wm + mi * 16 + rg + j;
        int n = bn + wn + ni * 16 + cl;
        __hip_atomic_fetch_add(&Rf[m * 256 + n], acc[mi][ni][j],
                               __ATOMIC_RELAXED, __HIP_MEMORY_SCOPE_AGENT);
      }
}

// ---------------- persistent RNN: r0=relu(Z); 9x r = relu(r@W + b_in + r); out-proj ----------------
// 256 blocks x 512 threads; block owns 32 rows. W lives in VGPRs (128/wave).
__global__ __launch_bounds__(512, 2) void rnn_persist_kernel(
    const float*    __restrict__ Rf,   // Z [8192][256] (pre-activation, bias included)
    const _Float16* __restrict__ Wt,   // [256][256] n-major, *2^12
    const float*    __restrict__ b_in, // [256]
    const float*    __restrict__ Wo,   // [10][256]
    const float*    __restrict__ bo,   // [10]
    float*          __restrict__ out)  // [8192][10]
{
  // element (row,k) stored at row*256 + (k ^ ((row&7)<<3))  [16B-granular]
  __shared__ __align__(16) _Float16 r_lds[32 * 256];
  int tid = threadIdx.x, lane = tid & 63, wid = tid >> 6;
  int wr = wid >> 2, wc = wid & 3;       // 2M x 4N wave grid; region 16r x 64c
  int bm = blockIdx.x * 32;

  // ---- W fragments -> registers (one-time) ----
  f16x8 wfr[8][4];
#pragma unroll
  for (int kk = 0; kk < 8; ++kk)
#pragma unroll
    for (int ni = 0; ni < 4; ++ni) {
      int n = wc * 64 + ni * 16 + (lane & 15);
      int kpos = kk * 32 + (lane >> 4) * 8;
      wfr[kk][ni] = *(const f16x8*)(Wt + n * 256 + kpos);
    }

  // ---- bias + f32 residual (relu applied here) -> registers ----
  float breg[4];
  float rres[4][4];
  int rrow = wr * 16 + (lane >> 4) * 4;
#pragma unroll
  for (int ni = 0; ni < 4; ++ni) {
    int col = wc * 64 + ni * 16 + (lane & 15);
    breg[ni] = b_in[col];
#pragma unroll
    for (int j = 0; j < 4; ++j)
      rres[ni][j] = fmaxf(Rf[(size_t)(bm + rrow + j) * 256 + col], 0.f);
  }

  // ---- r0 = relu(Z) f16 -> LDS (swizzled): 1024 vec8, 512 threads x 2 ----
#pragma unroll
  for (int it = 0; it < 2; ++it) {
    int idx = it * 512 + tid;            // 0..1023
    int row = idx >> 5;                  // 0..31
    int kc = (idx & 31) * 8;             // 0..248
    const float* src = Rf + (size_t)(bm + row) * 256 + kc;
    f32x4 v0 = *(const f32x4*)src;
    f32x4 v1 = *(const f32x4*)(src + 4);
    f16x8 h;
#pragma unroll
    for (int j = 0; j < 4; ++j) h[j] = (_Float16)fmaxf(v0[j], 0.f);
#pragma unroll
    for (int j = 0; j < 4; ++j) h[4 + j] = (_Float16)fmaxf(v1[j], 0.f);
    *(f16x8*)(r_lds + row * 256 + (kc ^ ((row & 7) << 3))) = h;
  }

  int arow = wr * 16 + (lane & 15);
  int aswz = (arow & 7) << 3;
  for (int s = 0; s < 9; ++s) {
    __syncthreads();                     // r_lds writes visible
    f32x4 acc[4];
#pragma unroll
    for (int ni = 0; ni < 4; ++ni) acc[ni] = (f32x4){0.f, 0.f, 0.f, 0.f};
#pragma unroll
    for (int kk = 0; kk < 8; ++kk) {
      int kpos = kk * 32 + (lane >> 4) * 8;
      f16x8 af = *(const f16x8*)(r_lds + arow * 256 + (kpos ^ aswz));
#pragma unroll
      for (int ni = 0; ni < 4; ++ni)
        acc[ni] = __builtin_amdgcn_mfma_f32_16x16x32_f16(af, wfr[kk][ni], acc[ni], 0, 0, 0);
    }
    __syncthreads();                     // all reads done before overwrite
#pragma unroll
    for (int ni = 0; ni < 4; ++ni) {
      int col = wc * 64 + ni * 16 + (lane & 15);
#pragma unroll
      for (int j = 0; j < 4; ++j) {
        float v = fmaxf(fmaf(acc[ni][j], W_UNSCALE, breg[ni] + rres[ni][j]), 0.f);
        rres[ni][j] = v;
        int row = rrow + j;
        r_lds[row * 256 + (col ^ ((row & 7) << 3))] = (_Float16)v;
      }
    }
  }
  __syncthreads();

  // ---- fused out-proj: out[32r][10] = r @ Wo^T + bo ----
  if (tid < 320) {
    int row = tid / 10, o = tid - row * 10;
    int rswz = (row & 7) << 3;
    float accd = 0.f;
    for (int kc = 0; kc < 256; kc += 8) {
      f16x8 rv = *(const f16x8*)(r_lds + row * 256 + (kc ^ rswz));
      const float* wp = Wo + o * 256 + kc;
#pragma unroll
      for (int j = 0; j < 8; ++j) accd = fmaf((float)rv[j], wp[j], accd);
    }
    out[(size_t)(bm + row) * 10 + o] = accd + bo[o];
  }
}

extern "C" void kernel_launch(void* const* d_in, const int* in_sizes, int n_in,
                              void* d_out, int out_size, void* d_ws, size_t ws_size,
                              hipStream_t stream) {
  const float* x      = (const float*)d_in[0];
  const float* conv_w = (const float*)d_in[1];
  const float* conv_b = (const float*)d_in[2];
  const float* W_in   = (const float*)d_in[3];
  const float* b_in   = (const float*)d_in[4];
  const float* W_out  = (const float*)d_in[5];
  const float* b_out  = (const float*)d_in[6];
  const float* W      = (const float*)d_in[7];
  float* out = (float*)d_out;

  char* ws = (char*)d_ws;
  size_t o = 0;
  _Float16* conv_flat = (_Float16*)(ws + o); o += (size_t)8192 * 3136 * 2;  // A' 51.4MB
  _Float16* W_in_h    = (_Float16*)(ws + o); o += (size_t)256 * 3136 * 2;   // B'  1.6MB
  _Float16* Wt_h      = (_Float16*)(ws + o); o += (size_t)256 * 256 * 2;    //     0.13MB
  float*    Rf0       = (float*)(ws + o);    o += (size_t)8192 * 256 * 4;   // Z   8.4MB

  win_cvt_kernel<<<256, 256, 0, stream>>>(W_in, W_in_h);
  wt_cvt_kernel<<<256, 256, 0, stream>>>(W, Wt_h);
  init_rf_kernel<<<2048, 256, 0, stream>>>(b_in, Rf0);
  conv_pool_kernel<<<8192, 256, 0, stream>>>(x, conv_w, conv_b, conv_flat);
  gemm1_kernel<<<dim3(128, 2, 7), 256, 0, stream>>>(conv_flat, W_in_h, Rf0);
  rnn_persist_kernel<<<256, 512, 0, stream>>>(Rf0, Wt_h, b_in, W_out, b_out, out);
}

// Round 9
// 166.764 us; speedup vs baseline: 1.3539x; 1.3539x over previous
//
#include <hip/hip_runtime.h>

typedef _Float16 f16x8 __attribute__((ext_vector_type(8)));
typedef _Float16 f16x4 __attribute__((ext_vector_type(4)));
typedef _Float16 h2   __attribute__((ext_vector_type(2)));
typedef float f32x4 __attribute__((ext_vector_type(4)));

__device__ __forceinline__ void gload16(const void* g, void* l) {
  __builtin_amdgcn_global_load_lds(
      (__attribute__((address_space(1))) void*)g,
      (__attribute__((address_space(3))) void*)l, 16, 0, 0);
}

// W is scaled by 2^12 when cast to f16 (raw ~1e-5 values are f16-subnormal;
// denormal flush would delete the r@W term). Epilogue multiplies by 2^-12.
#define W_SCALE 4096.0f
#define W_UNSCALE (1.0f / 4096.0f)

// "Island" layout (LDS-fragment-exact) — used ONLY for W_in (B operand), whose
// producer cost is trivial. element (row,k) -> (row>>4)*50176 + (k>>5)*512 +
// ((k>>3)&3)*128 + (row&15)*8 + (k&7).
#define ISL(row, k) (((row) >> 4) * 50176 + ((k) >> 5) * 512 + \
                     ((((k) >> 3) & 3) << 7) + (((row) & 15) << 3) + ((k) & 7))

// ---------------- conv 3x3 (1->16) + bias + relu + maxpool2 -> conv_flat (PLAIN) ----------
// one block per image; padded image staged in LDS; packed-f16 pool-pair math;
// plain row-major output (block-contiguous 6272B -> no cross-block line sharing).
__global__ __launch_bounds__(256) void conv_pool_kernel(
    const float* __restrict__ x,      // [8192][28][28]
    const float* __restrict__ cw,     // [16][9]
    const float* __restrict__ cb,     // [16]
    _Float16* __restrict__ out) {     // [8192][3136] plain (c*196 + p)
  __shared__ float img[30 * 32];      // padded 30 rows x 32 cols (row/col +1 offset)
  __shared__ h2 wsm[144];
  __shared__ h2 bsm[16];
  int tid = threadIdx.x;
  for (int i = tid; i < 960; i += 256) img[i] = 0.f;
  if (tid < 144) { float w = cw[tid]; wsm[tid] = h2{(_Float16)w, (_Float16)w}; }
  if (tid < 16)  { float b = cb[tid]; bsm[tid] = h2{(_Float16)b, (_Float16)b}; }
  __syncthreads();                    // zeros + weights visible
  if (tid < 196) {                    // 28 rows x 7 float4 per row (28 = 7*4 exact)
    float4 v = *(const float4*)(x + (size_t)blockIdx.x * 784 + tid * 4);
    int row = tid / 7, col4 = (tid - row * 7) * 4;
    float* dst = img + (row + 1) * 32 + col4 + 1;
    dst[0] = v.x; dst[1] = v.y; dst[2] = v.z; dst[3] = v.w;
  }
  __syncthreads();
  if (tid >= 196) return;
  int ph = tid / 14, pw = tid - ph * 14;
  const float* base = img + (2 * ph) * 32 + (2 * pw);   // logical (r,c)=(-1,-1) of patch
  h2 xp[4][3];                        // xp[i][j] = (patch[i][j], patch[i][j+1])
#pragma unroll
  for (int i = 0; i < 4; ++i) {
    float r0 = base[i * 32 + 0], r1 = base[i * 32 + 1];
    float r2 = base[i * 32 + 2], r3 = base[i * 32 + 3];
    xp[i][0] = h2{(_Float16)r0, (_Float16)r1};
    xp[i][1] = h2{(_Float16)r1, (_Float16)r2};
    xp[i][2] = h2{(_Float16)r2, (_Float16)r3};
  }
  _Float16* orow = out + (size_t)blockIdx.x * 3136 + tid;
#pragma unroll
  for (int ch = 0; ch < 16; ++ch) {
    h2 a01 = bsm[ch], a23 = bsm[ch];
#pragma unroll
    for (int i = 0; i < 3; ++i)
#pragma unroll
      for (int j = 0; j < 3; ++j) {
        h2 wv = wsm[ch * 9 + i * 3 + j];
        a01 = __builtin_elementwise_fma(wv, xp[i][j], a01);
        a23 = __builtin_elementwise_fma(wv, xp[i + 1][j], a23);
      }
    h2 m2 = __builtin_elementwise_max(a01, a23);
    _Float16 m = m2[0] > m2[1] ? m2[0] : m2[1];
    m = m > (_Float16)0.f ? m : (_Float16)0.f;  // relu(max) == max(relu)
    orow[ch * 196] = m;               // wave: 64 x 2B contiguous per ch
  }
}

// ---------------- W_in fp32 -> f16 island layout (B operand) ----------------
__global__ __launch_bounds__(256) void win_cvt_kernel(
    const float* __restrict__ in,     // [256][3136]
    _Float16* __restrict__ out) {     // island, logical [256][3136]
  int n = blockIdx.x, tid = threadIdx.x;
  const float* src = in + (size_t)n * 3136;
#pragma unroll
  for (int it = 0; it < 4; ++it) {
    int idx = it * 256 + tid;          // float4 index, 784 per row
    if (idx < 784) {
      int k0 = idx * 4;
      float4 v = *(const float4*)(src + k0);
      f16x4 h = {(_Float16)v.x, (_Float16)v.y, (_Float16)v.z, (_Float16)v.w};
      *(f16x4*)(out + ISL(n, k0)) = h;
    }
  }
}

// W [256][256] (k-major) -> Wt f16 [n][k] (n-major, plain), scaled by 2^12
__global__ void wt_cvt_kernel(const float* __restrict__ W,
                              _Float16* __restrict__ Wt) {
  int i = blockIdx.x * 256 + threadIdx.x;  // 65536
  int k = i >> 8, n = i & 255;             // coalesced read of W row k
  Wt[n * 256 + k] = (_Float16)(W[k * 256 + n] * W_SCALE);
}

// ---------------- GEMM1 split-K=2, NO atomics: Zz = A @ W_in^T (k-half z) ---------------
// grid (128,4,2); tile 64x64, BK=32, 49 steps; 4 waves x (32x32 = 2x2 frags).
// A: plain global, reg-staged -> island ds_write (1-step prefetch).
// B: island global -> global_load_lds direct.
__global__ __launch_bounds__(256) void gemm1_kernel(
    const _Float16* __restrict__ A,   // plain [8192][3136]
    const _Float16* __restrict__ Bw,  // island, logical [256][3136]
    float* __restrict__ Z) {          // [2][8192][256] partials
  __shared__ __align__(16) _Float16 As[2048];   // 4 chunks [kg][row][8]
  __shared__ __align__(16) _Float16 Bs[2048];
  int tid = threadIdx.x, lane = tid & 63, wid = tid >> 6;
  int bm = blockIdx.x * 64, bn = blockIdx.y * 64;
  int k0 = blockIdx.z * 1568;
  f32x4 acc[2][2];
#pragma unroll
  for (int i = 0; i < 2; ++i)
#pragma unroll
    for (int j = 0; j < 2; ++j) acc[i][j] = (f32x4){0.f, 0.f, 0.f, 0.f};

  int ar = tid >> 2;                   // A row 0..63 (4 threads per row)
  const _Float16* Ag = A + (size_t)(bm + ar) * 3136 + k0 + (tid & 3) * 8;
  _Float16* asw = As + (ar >> 4) * 512 + (tid & 3) * 128 + (ar & 15) * 8;
  const _Float16* Bg = Bw + ((bn >> 4) + wid) * 50176 + (k0 >> 5) * 512 + lane * 8;
  _Float16* bsw = Bs + wid * 512;

  int rko = ((lane >> 4) << 7) + ((lane & 15) << 3);
  int ga = (wid & 1) * 2, gb = (wid >> 1) * 2;

  f16x8 areg = *(const f16x8*)Ag;      // prefetch t=0
  for (int t = 0; t < 49; ++t) {
    __syncthreads();                   // prev-step readers done
    *(f16x8*)asw = areg;
    gload16(Bg + t * 512, bsw);
    if (t < 48) areg = *(const f16x8*)(Ag + (t + 1) * 32);  // hide A latency
    __syncthreads();                   // stage complete (vmcnt+lgkm drain)
    f16x8 af0 = *(const f16x8*)(As + (ga + 0) * 512 + rko);
    f16x8 af1 = *(const f16x8*)(As + (ga + 1) * 512 + rko);
    f16x8 bf0 = *(const f16x8*)(Bs + (gb + 0) * 512 + rko);
    f16x8 bf1 = *(const f16x8*)(Bs + (gb + 1) * 512 + rko);
    acc[0][0] = __builtin_amdgcn_mfma_f32_16x16x32_f16(af0, bf0, acc[0][0], 0, 0, 0);
    acc[0][1] = __builtin_amdgcn_mfma_f32_16x16x32_f16(af0, bf1, acc[0][1], 0, 0, 0);
    acc[1][0] = __builtin_amdgcn_mfma_f32_16x16x32_f16(af1, bf0, acc[1][0], 0, 0, 0);
    acc[1][1] = __builtin_amdgcn_mfma_f32_16x16x32_f16(af1, bf1, acc[1][1], 0, 0, 0);
  }
  float* Zp = Z + (size_t)blockIdx.z * 8192 * 256;
  int wm = (wid & 1) * 32, wn = (wid >> 1) * 32;
  int rg = (lane >> 4) * 4, cl = lane & 15;
#pragma unroll
  for (int mi = 0; mi < 2; ++mi)
#pragma unroll
    for (int ni = 0; ni < 2; ++ni)
#pragma unroll
      for (int j = 0; j < 4; ++j) {
        int m = bm + wm + mi * 16 + rg + j;
        int n = bn + wn + ni * 16 + cl;
        Zp[(size_t)m * 256 + n] = acc[mi][ni][j];
      }
}

// ---------------- persistent RNN: r0=relu(Z0+Z1+b); 9x r=relu(r@W+b+r); out-proj -------
// 256 blocks x 512 threads; block owns 32 rows. W lives in VGPRs (128/wave).
__global__ __launch_bounds__(512, 2) void rnn_persist_kernel(
    const float*    __restrict__ Z0,   // [8192][256] k-half 0 partial
    const float*    __restrict__ Z1,   // [8192][256] k-half 1 partial
    const _Float16* __restrict__ Wt,   // [256][256] n-major, *2^12
    const float*    __restrict__ b_in, // [256]
    const float*    __restrict__ Wo,   // [10][256]
    const float*    __restrict__ bo,   // [10]
    float*          __restrict__ out)  // [8192][10]
{
  // element (row,k) stored at row*256 + (k ^ ((row&7)<<3))  [16B-granular]
  __shared__ __align__(16) _Float16 r_lds[32 * 256];
  int tid = threadIdx.x, lane = tid & 63, wid = tid >> 6;
  int wr = wid >> 2, wc = wid & 3;       // 2M x 4N wave grid; region 16r x 64c
  int bm = blockIdx.x * 32;

  // ---- W fragments -> registers (one-time) ----
  f16x8 wfr[8][4];
#pragma unroll
  for (int kk = 0; kk < 8; ++kk)
#pragma unroll
    for (int ni = 0; ni < 4; ++ni) {
      int n = wc * 64 + ni * 16 + (lane & 15);
      int kpos = kk * 32 + (lane >> 4) * 8;
      wfr[kk][ni] = *(const f16x8*)(Wt + n * 256 + kpos);
    }

  // ---- bias + f32 residual r0 = relu(Z0+Z1+b) -> registers ----
  float breg[4];
  float rres[4][4];
  int rrow = wr * 16 + (lane >> 4) * 4;
#pragma unroll
  for (int ni = 0; ni < 4; ++ni) {
    int col = wc * 64 + ni * 16 + (lane & 15);
    breg[ni] = b_in[col];
#pragma unroll
    for (int j = 0; j < 4; ++j) {
      size_t idx = (size_t)(bm + rrow + j) * 256 + col;
      rres[ni][j] = fmaxf(Z0[idx] + Z1[idx] + breg[ni], 0.f);
    }
  }

  // ---- r0 f16 -> LDS (swizzled): 1024 vec8, 512 threads x 2 ----
#pragma unroll
  for (int it = 0; it < 2; ++it) {
    int idx = it * 512 + tid;            // 0..1023
    int row = idx >> 5;                  // 0..31
    int kc = (idx & 31) * 8;             // 0..248
    size_t off = (size_t)(bm + row) * 256 + kc;
    f32x4 a0 = *(const f32x4*)(Z0 + off);
    f32x4 a1 = *(const f32x4*)(Z0 + off + 4);
    f32x4 b0 = *(const f32x4*)(Z1 + off);
    f32x4 b1 = *(const f32x4*)(Z1 + off + 4);
    f32x4 c0 = *(const f32x4*)(b_in + kc);
    f32x4 c1 = *(const f32x4*)(b_in + kc + 4);
    f16x8 h;
#pragma unroll
    for (int j = 0; j < 4; ++j) h[j] = (_Float16)fmaxf(a0[j] + b0[j] + c0[j], 0.f);
#pragma unroll
    for (int j = 0; j < 4; ++j) h[4 + j] = (_Float16)fmaxf(a1[j] + b1[j] + c1[j], 0.f);
    *(f16x8*)(r_lds + row * 256 + (kc ^ ((row & 7) << 3))) = h;
  }

  int arow = wr * 16 + (lane & 15);
  int aswz = (arow & 7) << 3;
  for (int s = 0; s < 9; ++s) {
    __syncthreads();                     // r_lds writes visible
    f32x4 acc[4];
#pragma unroll
    for (int ni = 0; ni < 4; ++ni) acc[ni] = (f32x4){0.f, 0.f, 0.f, 0.f};
#pragma unroll
    for (int kk = 0; kk < 8; ++kk) {
      int kpos = kk * 32 + (lane >> 4) * 8;
      f16x8 af = *(const f16x8*)(r_lds + arow * 256 + (kpos ^ aswz));
#pragma unroll
      for (int ni = 0; ni < 4; ++ni)
        acc[ni] = __builtin_amdgcn_mfma_f32_16x16x32_f16(af, wfr[kk][ni], acc[ni], 0, 0, 0);
    }
    __syncthreads();                     // all reads done before overwrite
#pragma unroll
    for (int ni = 0; ni < 4; ++ni) {
      int col = wc * 64 + ni * 16 + (lane & 15);
#pragma unroll
      for (int j = 0; j < 4; ++j) {
        float v = fmaxf(fmaf(acc[ni][j], W_UNSCALE, breg[ni] + rres[ni][j]), 0.f);
        rres[ni][j] = v;
        int row = rrow + j;
        r_lds[row * 256 + (col ^ ((row & 7) << 3))] = (_Float16)v;
      }
    }
  }
  __syncthreads();

  // ---- fused out-proj: out[32r][10] = r @ Wo^T + bo ----
  if (tid < 320) {
    int row = tid / 10, o = tid - row * 10;
    int rswz = (row & 7) << 3;
    float accd = 0.f;
    for (int kc = 0; kc < 256; kc += 8) {
      f16x8 rv = *(const f16x8*)(r_lds + row * 256 + (kc ^ rswz));
      const float* wp = Wo + o * 256 + kc;
#pragma unroll
      for (int j = 0; j < 8; ++j) accd = fmaf((float)rv[j], wp[j], accd);
    }
    out[(size_t)(bm + row) * 10 + o] = accd + bo[o];
  }
}

extern "C" void kernel_launch(void* const* d_in, const int* in_sizes, int n_in,
                              void* d_out, int out_size, void* d_ws, size_t ws_size,
                              hipStream_t stream) {
  const float* x      = (const float*)d_in[0];
  const float* conv_w = (const float*)d_in[1];
  const float* conv_b = (const float*)d_in[2];
  const float* W_in   = (const float*)d_in[3];
  const float* b_in   = (const float*)d_in[4];
  const float* W_out  = (const float*)d_in[5];
  const float* b_out  = (const float*)d_in[6];
  const float* W      = (const float*)d_in[7];
  float* out = (float*)d_out;

  char* ws = (char*)d_ws;
  size_t o = 0;
  _Float16* conv_flat = (_Float16*)(ws + o); o += (size_t)8192 * 3136 * 2;  // 51.4MB plain
  _Float16* W_in_h    = (_Float16*)(ws + o); o += (size_t)256 * 3136 * 2;   //  1.6MB island
  _Float16* Wt_h      = (_Float16*)(ws + o); o += (size_t)256 * 256 * 2;    //  0.13MB
  float*    Z01       = (float*)(ws + o);    o += (size_t)2 * 8192 * 256 * 4; // 16.8MB partials

  win_cvt_kernel<<<256, 256, 0, stream>>>(W_in, W_in_h);
  wt_cvt_kernel<<<256, 256, 0, stream>>>(W, Wt_h);
  conv_pool_kernel<<<8192, 256, 0, stream>>>(x, conv_w, conv_b, conv_flat);
  gemm1_kernel<<<dim3(128, 4, 2), 256, 0, stream>>>(conv_flat, W_in_h, Z01);
  rnn_persist_kernel<<<256, 512, 0, stream>>>(Z01, Z01 + (size_t)8192 * 256,
                                              Wt_h, b_in, W_out, b_out, out);
}